// Round 5
// baseline (268.427 us; speedup 1.0000x reference)
//
#include <hip/hip_runtime.h>

#define OUT_N 11008
#define IN_K  4096
#define BATCH 32
#define SEGS  8
#define KSEG  (IN_K / SEGS)   // 512 k per block
#define CK    64              // k per double-buffered chunk
#define NCH   (KSEG / CK)     // 8 chunks
#define OPB   64              // outputs per block (4 waves x 16 rows)
#define XSTR  516             // xs row stride (shorts): 258 words %32=2 -> <=4-way
#define WSTR  68              // wl row stride (shorts): 34 words %32=2 -> <=4-way

typedef __attribute__((ext_vector_type(8))) short short8;
typedef __attribute__((ext_vector_type(4))) float float4v;

// out[b][o] = bias[o]; main kernel atomically accumulates K-segment partials.
__global__ __launch_bounds__(256) void init_kernel(
    const float* __restrict__ bias, float* __restrict__ out)
{
    int i = blockIdx.x * 256 + threadIdx.x;
    if (i < BATCH * OUT_N) out[i] = bias[i % OUT_N];
}

// fp32 -> bf16 RNE
__device__ __forceinline__ unsigned short f2bf(float f) {
    unsigned u = __builtin_bit_cast(unsigned, f);
    unsigned r = u + 0x7FFFu + ((u >> 16) & 1u);
    return (unsigned short)(r >> 16);
}

// pack two fp32 (exact {-1,0,1}) into two bf16 by mantissa truncation
__device__ __forceinline__ unsigned pkbf16(float fhi, float flo) {
    return __builtin_amdgcn_perm(__builtin_bit_cast(unsigned, fhi),
                                 __builtin_bit_cast(unsigned, flo),
                                 0x07060302u);
}

// Block = 4 waves = 64 output rows x KSEG=512 k, processed as 8 double-buffered
// 64-k chunks: while chunk c is MFMA'd from wl[c&1], chunk c+1 (already in
// VGPRs) is converted+written to wl[(c+1)&1] and chunk c+2's global loads are
// issued -> continuous HBM demand, one barrier per chunk. One load inst covers
// 4 rows x 256 B contiguous (1 KB/wave-inst).
__global__ __launch_bounds__(256, 3) void lin2bit_kernel(
    const int* __restrict__ wq, const float* __restrict__ scale,
    const float* __restrict__ x, float* __restrict__ out)
{
    __shared__ unsigned short xs[BATCH][XSTR];     // 33024 B
    __shared__ unsigned short wl[2][OPB][WSTR];    // 17408 B -> 50432 total, 3 blk/CU

    const int t    = threadIdx.x;
    const int lane = t & 63;
    const int wave = t >> 6;
    const int kseg = blockIdx.y * KSEG;
    const int o0   = blockIdx.x * OPB;

    // --- stage x[0:32][kseg:+512] fp32 -> bf16 LDS (16 float4 per thread) ---
#pragma unroll
    for (int it = 0; it < 16; ++it) {
        int idx = it * 256 + t;
        int b   = idx >> 7;            // 128 float4 per row
        int k4  = idx & 127;
        float4 v = *reinterpret_cast<const float4*>(x + b * IN_K + kseg + k4 * 4);
        ushort4 h = { f2bf(v.x), f2bf(v.y), f2bf(v.z), f2bf(v.w) };
        *reinterpret_cast<ushort4*>(&xs[b][k4 * 4]) = h;
    }

    // --- W chunk staging helpers: wave owns rows [wave*16, wave*16+16) ---
    const int rsub = lane >> 4;        // row within 4-row group
    const int csub = lane & 15;        // int4 column within 64-int chunk
    const int* __restrict__ wbase =
        wq + (size_t)(o0 + wave * 16 + rsub) * IN_K + kseg + csub * 4;

#define WLOAD(c, r)                                                           \
    do {                                                                      \
        _Pragma("unroll")                                                     \
        for (int j = 0; j < 4; ++j)                                           \
            (r)[j] = *reinterpret_cast<const int4*>(                          \
                wbase + (size_t)(j * 4) * IN_K + (c) * CK);                   \
    } while (0)

#define WSTORE(c, r)                                                          \
    do {                                                                      \
        _Pragma("unroll")                                                     \
        for (int j = 0; j < 4; ++j) {                                         \
            unsigned lo = pkbf16((float)(r)[j].y, (float)(r)[j].x);           \
            unsigned hi = pkbf16((float)(r)[j].w, (float)(r)[j].z);           \
            uint2 p = { lo, hi };                                             \
            *reinterpret_cast<uint2*>(                                        \
                &wl[(c) & 1][wave * 16 + j * 4 + rsub][csub * 4]) = p;        \
        }                                                                     \
    } while (0)

    int4 cur[4], nxt[4];
    WLOAD(0, cur);
    WSTORE(0, cur);        // waits for chunk-0 loads, fills wl[0]
    WLOAD(1, nxt);         // chunk-1 loads in flight across the barrier
    __syncthreads();       // xs + wl[0] visible

    const int quad = lane >> 4;
    const int l16  = lane & 15;
    const int o    = o0 + wave * 16 + l16;

    float4v acc0 = {0.f, 0.f, 0.f, 0.f};
    float4v acc1 = {0.f, 0.f, 0.f, 0.f};

    for (int c = 0; c < NCH; ++c) {
        const unsigned short* wrow = &wl[c & 1][wave * 16 + l16][quad * 8];
        const unsigned short* x0   = &xs[l16][c * CK + quad * 8];
        const unsigned short* x1   = &xs[l16 + 16][c * CK + quad * 8];
#pragma unroll
        for (int kt = 0; kt < CK / 32; ++kt) {
            short8 bfrag = *reinterpret_cast<const short8*>(wrow + kt * 32);
            short8 a0    = *reinterpret_cast<const short8*>(x0 + kt * 32);
            short8 a1    = *reinterpret_cast<const short8*>(x1 + kt * 32);
            acc0 = __builtin_amdgcn_mfma_f32_16x16x32_bf16(a0, bfrag, acc0, 0, 0, 0);
            acc1 = __builtin_amdgcn_mfma_f32_16x16x32_bf16(a1, bfrag, acc1, 0, 0, 0);
        }
        if (c + 1 < NCH) {
#pragma unroll
            for (int j = 0; j < 4; ++j) cur[j] = nxt[j];
            WSTORE(c + 1, cur);                 // fill other buffer
            if (c + 2 < NCH) WLOAD(c + 2, nxt); // keep loads in flight
        }
        __syncthreads();
    }
#undef WLOAD
#undef WSTORE

    // C/D layout: col(o) = lane&15, row(b) = quad*4 + reg
    const float s = scale[o];
    const int b0 = quad * 4;
#pragma unroll
    for (int r = 0; r < 4; ++r) {
        unsafeAtomicAdd(out + (size_t)(b0 + r)      * OUT_N + o, s * acc0[r]);
        unsafeAtomicAdd(out + (size_t)(b0 + r + 16) * OUT_N + o, s * acc1[r]);
    }
}

extern "C" void kernel_launch(void* const* d_in, const int* in_sizes, int n_in,
                              void* d_out, int out_size, void* d_ws, size_t ws_size,
                              hipStream_t stream) {
    const float* x     = (const float*)d_in[0];
    const int*   wq    = (const int*)d_in[1];
    const float* scale = (const float*)d_in[2];
    const float* bias  = (const float*)d_in[3];
    float* out = (float*)d_out;

    init_kernel<<<dim3((BATCH * OUT_N + 255) / 256), 256, 0, stream>>>(bias, out);
    lin2bit_kernel<<<dim3(OUT_N / OPB, SEGS), 256, 0, stream>>>(wq, scale, x, out);
}